// Round 8
// baseline (56.026 us; speedup 1.0000x reference)
//
#include <hip/hip_runtime.h>
#include <hip/hip_bf16.h>

// logits[b,r,l,t] = sum_h hs[b,l,h]*W[r,t,h] + bias[r,t]; softmax over t(3).
// M = 66048 tokens, K = 768, N = 72 (5 n-tiles of 16, last half-padded).
//
// Round 8: K-split TLP. 2-wave blocks over the SAME 32 tokens; wave w does
// k-steps [12w, 12w+12). 2064 blocks x 128 thr = 4128 waves = 16 waves/CU
// (was 8) at IDENTICAL global traffic (A: disjoint K-halves; B: each wave
// reads only its half of ws). Combine: wave0 writes 40 acc dwords/lane to
// LDS lane-major (conflict-free, no transpose), wave1 adds in-register,
// transposes (stride 85), both waves split the softmax. VGPR kept <= 128
// (R5 buffer config: A depth-2, B depth-1) so 4 waves/SIMD fit.
// A path: per-lane-contiguous fp32 loads, HW cvt -> bf16, verified
// ds_bpermute map src = 4*(t&15) + (t>>4). B preconverted frag-order in ws.

#define HD     768
#define LSEQ   8256
#define RREL   24
#define KSTEPS 24      // 768/32 total
#define WKS    12      // k-steps per wave (K split in half)
#define NT     5       // n-tiles of 16 covering 72 (tile 4 half-padded)
#define NCOL   72

typedef float f32x4 __attribute__((ext_vector_type(4)));
typedef short s16x8 __attribute__((ext_vector_type(8)));
typedef int   i32x4 __attribute__((ext_vector_type(4)));

__device__ __forceinline__ unsigned f2bf_rne(float f) {  // conv_w only
  unsigned u = __builtin_bit_cast(unsigned, f);
  u += 0x7FFFu + ((u >> 16) & 1u);
  return u >> 16;
}

// hot path: HW cvt (RNE); packed dword via integer ops
__device__ __forceinline__ int pack2(float lo, float hi) {
  unsigned l = __bfloat16_as_ushort(__float2bfloat16(lo));
  unsigned h = __bfloat16_as_ushort(__float2bfloat16(hi));
  return (int)(l | (h << 16));
}

// ---- kernel 1: W (24,3,768) fp32 -> bf16 fragment-order ws ----
// ws chunk idx = (ks*NT + nt)*64 + lane, holding 8 bf16:
//   col = nt*16 + (lane&15), k = ks*32 + (lane>>4)*8 + i   (0 if col>=72)
__global__ void conv_w_kernel(const float* __restrict__ W,
                              unsigned short* __restrict__ wsB) {
  int idx = blockIdx.x * 256 + threadIdx.x;       // [0, 7680)
  if (idx >= KSTEPS * NT * 64) return;
  int ks   = idx / (NT * 64);
  int rem  = idx - ks * (NT * 64);
  int nt   = rem >> 6;
  int lane = rem & 63;
  int col  = nt * 16 + (lane & 15);
  int k0   = ks * 32 + (lane >> 4) * 8;
  unsigned short v[8] = {0, 0, 0, 0, 0, 0, 0, 0};
  if (col < NCOL) {
    const float* p = W + (size_t)col * HD + k0;
    float4 a = *(const float4*)p;
    float4 b = *(const float4*)(p + 4);
    v[0] = (unsigned short)f2bf_rne(a.x); v[1] = (unsigned short)f2bf_rne(a.y);
    v[2] = (unsigned short)f2bf_rne(a.z); v[3] = (unsigned short)f2bf_rne(a.w);
    v[4] = (unsigned short)f2bf_rne(b.x); v[5] = (unsigned short)f2bf_rne(b.y);
    v[6] = (unsigned short)f2bf_rne(b.z); v[7] = (unsigned short)f2bf_rne(b.w);
  }
  *(s16x8*)(wsB + (size_t)idx * 8) = *(s16x8*)v;
}

// ---- shared macros (ks is wave-relative, 0..WKS-1) ----
#define ALOAD(ks, LIM) do { if ((ks) < (LIM)) {                    \
    const int s_ = (ks) % 3, o_ = (ks) * 32;                       \
    abuf[s_][0][0] = *(const float4*)(pA0 + o_);                   \
    abuf[s_][0][1] = *(const float4*)(pA0 + o_ + 4);               \
    abuf[s_][1][0] = *(const float4*)(pA1 + o_);                   \
    abuf[s_][1][1] = *(const float4*)(pA1 + o_ + 4);               \
  } } while (0)

#define BLOAD_WS(ks, LIM) do { if ((ks) < (LIM)) {                 \
    _Pragma("unroll")                                              \
    for (int nt_ = 0; nt_ < NT; ++nt_)                             \
      bbuf[(ks) & 1][nt_] = pW4[(ks) * NT * 64 + nt_ * 64 + lane]; \
  } } while (0)

#define AFRAG(ks, af)  do {                                        \
    _Pragma("unroll")                                              \
    for (int mt_ = 0; mt_ < 2; ++mt_) {                            \
      float4 a0 = abuf[(ks) % 3][mt_][0], a1 = abuf[(ks) % 3][mt_][1]; \
      i32x4 av;                                                    \
      av[0] = __builtin_amdgcn_ds_bpermute(bp, pack2(a0.x, a0.y)); \
      av[1] = __builtin_amdgcn_ds_bpermute(bp, pack2(a0.z, a0.w)); \
      av[2] = __builtin_amdgcn_ds_bpermute(bp, pack2(a1.x, a1.y)); \
      av[3] = __builtin_amdgcn_ds_bpermute(bp, pack2(a1.z, a1.w)); \
      (af)[mt_] = __builtin_bit_cast(s16x8, av);                   \
    }                                                              \
  } while (0)

// ---- main (ws path): 2-wave K-split blocks ----
__global__ __launch_bounds__(128, 4)
void tagging_ks(const float* __restrict__ hs, const float* __restrict__ bias,
                const i32x4* __restrict__ pWS, float* __restrict__ out) {
  __shared__ float sh[32 * 85];       // 10.9 KB: frag handoff (2560 floats)
                                      // then transposed logits (2720 floats)

  const int tid  = threadIdx.x;
  const int lane = tid & 63;
  const int wid  = tid >> 6;          // 0: k=[0,384), 1: k=[384,768)
  const int m0   = blockIdx.x * 32;   // 66048/32 = 2064 blocks, exact

  // A: per-lane contiguous 32B of row m0+(lane>>2)(+16), this wave's K-half
  const float* pA0 = hs + (size_t)(m0 + (lane >> 2)) * HD
                        + wid * (WKS * 32) + (lane & 3) * 8;
  const float* pA1 = pA0 + 16 * HD;
  // B: this wave's half of the frag-order ws image
  const i32x4* pW4 = pWS + (size_t)wid * WKS * NT * 64;
  // bpermute byte addr: target lane t pulls src lane 4*(t&15) + (t>>4)
  const int bp = ((lane & 15) * 4 + (lane >> 4)) * 4;

  f32x4  acc[2][NT] = {};             // 40 VGPR
  float4 abuf[3][2][2];               // A depth-2 (48 VGPR)
  i32x4  bbuf[2][NT];                 // B depth-1 (40 VGPR)

  ALOAD(0, WKS); ALOAD(1, WKS);
  BLOAD_WS(0, WKS);

  #pragma unroll
  for (int ks = 0; ks < WKS; ++ks) {
    ALOAD(ks + 2, WKS);
    BLOAD_WS(ks + 1, WKS);
    s16x8 af[2];
    AFRAG(ks, af);
    #pragma unroll
    for (int nt = 0; nt < NT; ++nt) {
      s16x8 bf = __builtin_bit_cast(s16x8, bbuf[ks & 1][nt]);
      acc[0][nt] = __builtin_amdgcn_mfma_f32_16x16x32_bf16(af[0], bf, acc[0][nt], 0, 0, 0);
      acc[1][nt] = __builtin_amdgcn_mfma_f32_16x16x32_bf16(af[1], bf, acc[1][nt], 0, 0, 0);
    }
  }

  // ---- combine: wave0 -> LDS (lane-major frag order, conflict-free) ----
  if (wid == 0) {
    #pragma unroll
    for (int mt = 0; mt < 2; ++mt)
      #pragma unroll
      for (int nt = 0; nt < NT; ++nt)
        #pragma unroll
        for (int j = 0; j < 4; ++j)
          sh[((mt * NT + nt) * 4 + j) * 64 + lane] = acc[mt][nt][j];
  }
  __syncthreads();

  if (wid == 1) {
    // add wave0's partials (all reads before any transpose write; runtime
    // indices into the same array keep the compiler from reordering across)
    #pragma unroll
    for (int mt = 0; mt < 2; ++mt)
      #pragma unroll
      for (int nt = 0; nt < NT; ++nt)
        #pragma unroll
        for (int j = 0; j < 4; ++j)
          acc[mt][nt][j] += sh[((mt * NT + nt) * 4 + j) * 64 + lane];
    // transpose combined logits: C/D layout col = lane&15, row = 4*(lane>>4)+j
    #pragma unroll
    for (int mt = 0; mt < 2; ++mt)
      #pragma unroll
      for (int nt = 0; nt < NT; ++nt)
        #pragma unroll
        for (int j = 0; j < 4; ++j)
          sh[(mt * 16 + (lane >> 4) * 4 + j) * 85 + nt * 16 + (lane & 15)]
              = acc[mt][nt][j];
  }
  __syncthreads();

  // ---- softmax: both waves, 6 iterations each ----
  const int bidx = m0 / LSEQ;         // block-uniform: 8256 % 32 == 0
  const int l0   = m0 - bidx * LSEQ;
  #pragma unroll
  for (int it = 0; it < 6; ++it) {
    int flat = it * 128 + tid;        // [0,768) = 24 relations x 32 tokens
    int g    = flat >> 5;             // relation
    int tokl = flat & 31;
    const float* row = sh + tokl * 85;
    float x0 = row[3 * g + 0] + bias[3 * g + 0];
    float x1 = row[3 * g + 1] + bias[3 * g + 1];
    float x2 = row[3 * g + 2] + bias[3 * g + 2];
    float mx = fmaxf(x0, fmaxf(x1, x2));
    float e0 = __expf(x0 - mx), e1 = __expf(x1 - mx), e2 = __expf(x2 - mx);
    float inv = 1.0f / (e0 + e1 + e2);
    size_t o = ((size_t)(bidx * RREL + g) * LSEQ + l0 + tokl) * 3;
    out[o + 0] = e0 * inv;
    out[o + 1] = e1 * inv;
    out[o + 2] = e2 * inv;
  }
}

// ---- fallback (no ws): round-5 1-wave kernel with direct B loads ----
__global__ __launch_bounds__(64, 2)
void tagging_fb(const float* __restrict__ hs, const float* __restrict__ W,
                const float* __restrict__ bias, float* __restrict__ out) {
  __shared__ float lg[32][85];
  const int lane = threadIdx.x;
  const int m0   = blockIdx.x * 32;

  const float* pA0 = hs + (size_t)(m0 + (lane >> 2)) * HD + (lane & 3) * 8;
  const float* pA1 = pA0 + 16 * HD;
  const int bp = ((lane & 15) * 4 + (lane >> 4)) * 4;

  const float* pB[NT];
  #pragma unroll
  for (int nt = 0; nt < NT; ++nt)
    pB[nt] = W + (size_t)(nt * 16 + (lane & 15)) * HD + (lane >> 4) * 8;
  const bool b4ok = (lane & 15) < 8;

  f32x4  acc[2][NT] = {};
  float4 abuf[3][2][2];
  float4 fbf[2][NT][2];

#define FB_BLOAD(ks) do { if ((ks) < KSTEPS) {                     \
    _Pragma("unroll")                                              \
    for (int nt_ = 0; nt_ < 4; ++nt_) {                            \
      fbf[(ks) & 1][nt_][0] = *(const float4*)(pB[nt_] + (ks)*32); \
      fbf[(ks) & 1][nt_][1] = *(const float4*)(pB[nt_] + (ks)*32 + 4); \
    }                                                              \
    if (b4ok) {                                                    \
      fbf[(ks) & 1][4][0] = *(const float4*)(pB[4] + (ks)*32);     \
      fbf[(ks) & 1][4][1] = *(const float4*)(pB[4] + (ks)*32 + 4); \
    } else {                                                       \
      fbf[(ks) & 1][4][0] = make_float4(0.f,0.f,0.f,0.f);          \
      fbf[(ks) & 1][4][1] = make_float4(0.f,0.f,0.f,0.f);          \
    }                                                              \
  } } while (0)

  ALOAD(0, KSTEPS); ALOAD(1, KSTEPS);
  FB_BLOAD(0);

  #pragma unroll
  for (int ks = 0; ks < KSTEPS; ++ks) {
    ALOAD(ks + 2, KSTEPS);
    FB_BLOAD(ks + 1);
    s16x8 af[2];
    AFRAG(ks, af);
    #pragma unroll
    for (int nt = 0; nt < NT; ++nt) {
      float4 b0 = fbf[ks & 1][nt][0], b1 = fbf[ks & 1][nt][1];
      i32x4 bv;
      bv[0] = pack2(b0.x, b0.y); bv[1] = pack2(b0.z, b0.w);
      bv[2] = pack2(b1.x, b1.y); bv[3] = pack2(b1.z, b1.w);
      s16x8 bf = __builtin_bit_cast(s16x8, bv);
      acc[0][nt] = __builtin_amdgcn_mfma_f32_16x16x32_bf16(af[0], bf, acc[0][nt], 0, 0, 0);
      acc[1][nt] = __builtin_amdgcn_mfma_f32_16x16x32_bf16(af[1], bf, acc[1][nt], 0, 0, 0);
    }
  }

  #pragma unroll
  for (int mt = 0; mt < 2; ++mt)
    #pragma unroll
    for (int nt = 0; nt < NT; ++nt)
      #pragma unroll
      for (int j = 0; j < 4; ++j)
        lg[mt * 16 + (lane >> 4) * 4 + j][nt * 16 + (lane & 15)] = acc[mt][nt][j];
  __syncthreads();

  const int bidx = m0 / LSEQ;
  const int l0   = m0 - bidx * LSEQ;
  #pragma unroll
  for (int it = 0; it < 12; ++it) {
    int flat = it * 64 + lane;
    int g    = flat >> 5;
    int tokl = flat & 31;
    float x0 = lg[tokl][3 * g + 0] + bias[3 * g + 0];
    float x1 = lg[tokl][3 * g + 1] + bias[3 * g + 1];
    float x2 = lg[tokl][3 * g + 2] + bias[3 * g + 2];
    float mx = fmaxf(x0, fmaxf(x1, x2));
    float e0 = __expf(x0 - mx), e1 = __expf(x1 - mx), e2 = __expf(x2 - mx);
    float inv = 1.0f / (e0 + e1 + e2);
    size_t o = ((size_t)(bidx * RREL + g) * LSEQ + l0 + tokl) * 3;
    out[o + 0] = e0 * inv;
    out[o + 1] = e1 * inv;
    out[o + 2] = e2 * inv;
  }
}

extern "C" void kernel_launch(void* const* d_in, const int* in_sizes, int n_in,
                              void* d_out, int out_size, void* d_ws, size_t ws_size,
                              hipStream_t stream) {
  (void)in_sizes; (void)n_in; (void)out_size;
  const float* hs   = (const float*)d_in[0];  // (8, 8256, 768) fp32
  const float* W    = (const float*)d_in[1];  // (24, 3, 768)   fp32
  const float* bias = (const float*)d_in[2];  // (24, 3)        fp32
  float* out = (float*)d_out;                 // (8, 24, 8256, 3) fp32

  const size_t needB = (size_t)KSTEPS * NT * 64 * 8 * 2;   // 122880 B
  if (d_ws && ws_size >= needB) {
    hipLaunchKernelGGL(conv_w_kernel, dim3(30), dim3(256), 0, stream,
                       W, (unsigned short*)d_ws);
    hipLaunchKernelGGL(tagging_ks, dim3(2064), dim3(128), 0, stream,
                       hs, bias, (const i32x4*)d_ws, out);
  } else {
    hipLaunchKernelGGL(tagging_fb, dim3(2064), dim3(64), 0, stream,
                       hs, W, bias, out);
  }
}

// Round 9
// 48.810 us; speedup vs baseline: 1.1478x; 1.1478x over previous
//
#include <hip/hip_runtime.h>
#include <hip/hip_bf16.h>

// logits[b,r,l,t] = sum_h hs[b,l,h]*W[r,t,h] + bias[r,t]; softmax over t(3).
// M = 66048 tokens, K = 768, N = 72 (5 n-tiles of 16, last half-padded).
//
// Round 9: 64 tokens/wave (4 m-frags share every B fragment). 1032 one-wave
// blocks = 4 waves/CU. Per-CU B flow halves vs R5 (480 KB), A flow same ->
// total delivered bytes/CU -27%. Tests the "per-CU delivered-bytes +
// queueing" limiter theory (R6 depth=null, R7 LDS=neg, R8 TLP=neg all
// killed the alternatives). VGPR ~236 (acc 80 + abuf 96 + bbuf 40),
// __launch_bounds__(64,1). A path: per-lane-contiguous 32B loads per
// 16-row phase, HW cvt -> bf16, verified ds_bpermute map
// src = 4*(t&15) + (t>>4). B preconverted bf16 frag-order in d_ws.

#define HD     768
#define LSEQ   8256
#define RREL   24
#define KSTEPS 24      // 768/32
#define NT     5       // n-tiles of 16 covering 72 (tile 4 half-padded)
#define NCOL   72
#define MF     4       // m-frags per wave (64 tokens)

typedef float f32x4 __attribute__((ext_vector_type(4)));
typedef short s16x8 __attribute__((ext_vector_type(8)));
typedef int   i32x4 __attribute__((ext_vector_type(4)));

__device__ __forceinline__ unsigned f2bf_rne(float f) {  // conv_w only
  unsigned u = __builtin_bit_cast(unsigned, f);
  u += 0x7FFFu + ((u >> 16) & 1u);
  return u >> 16;
}

// hot path: HW cvt (RNE); packed dword via integer ops
__device__ __forceinline__ int pack2(float lo, float hi) {
  unsigned l = __bfloat16_as_ushort(__float2bfloat16(lo));
  unsigned h = __bfloat16_as_ushort(__float2bfloat16(hi));
  return (int)(l | (h << 16));
}

// ---- kernel 1: W (24,3,768) fp32 -> bf16 fragment-order ws ----
// ws chunk idx = (ks*NT + nt)*64 + lane, holding 8 bf16:
//   col = nt*16 + (lane&15), k = ks*32 + (lane>>4)*8 + i   (0 if col>=72)
__global__ void conv_w_kernel(const float* __restrict__ W,
                              unsigned short* __restrict__ wsB) {
  int idx = blockIdx.x * 256 + threadIdx.x;       // [0, 7680)
  if (idx >= KSTEPS * NT * 64) return;
  int ks   = idx / (NT * 64);
  int rem  = idx - ks * (NT * 64);
  int nt   = rem >> 6;
  int lane = rem & 63;
  int col  = nt * 16 + (lane & 15);
  int k0   = ks * 32 + (lane >> 4) * 8;
  unsigned short v[8] = {0, 0, 0, 0, 0, 0, 0, 0};
  if (col < NCOL) {
    const float* p = W + (size_t)col * HD + k0;
    float4 a = *(const float4*)p;
    float4 b = *(const float4*)(p + 4);
    v[0] = (unsigned short)f2bf_rne(a.x); v[1] = (unsigned short)f2bf_rne(a.y);
    v[2] = (unsigned short)f2bf_rne(a.z); v[3] = (unsigned short)f2bf_rne(a.w);
    v[4] = (unsigned short)f2bf_rne(b.x); v[5] = (unsigned short)f2bf_rne(b.y);
    v[6] = (unsigned short)f2bf_rne(b.z); v[7] = (unsigned short)f2bf_rne(b.w);
  }
  *(s16x8*)(wsB + (size_t)idx * 8) = *(s16x8*)v;
}

// ---- main: 64 tokens/wave, 1-wave blocks ----
#define ALOAD4(ks) do { if ((ks) < KSTEPS) {                       \
    const int s_ = (ks) % 3, o_ = (ks) * 32;                       \
    _Pragma("unroll")                                              \
    for (int ph_ = 0; ph_ < MF; ++ph_) {                           \
      abuf[s_][ph_][0] = *(const float4*)(pA[ph_] + o_);           \
      abuf[s_][ph_][1] = *(const float4*)(pA[ph_] + o_ + 4);       \
    }                                                              \
  } } while (0)

#define BLOAD4(ks) do { if ((ks) < KSTEPS) {                       \
    _Pragma("unroll")                                              \
    for (int nt_ = 0; nt_ < NT; ++nt_)                             \
      bbuf[(ks) & 1][nt_] = pWS[(ks) * NT * 64 + nt_ * 64 + lane]; \
  } } while (0)

__global__ __launch_bounds__(64, 1)
void tagging_m64(const float* __restrict__ hs, const float* __restrict__ bias,
                 const i32x4* __restrict__ pWS, float* __restrict__ out) {
  __shared__ float lg[64][85];        // 21.76 KB; stride 85 (85%32=21, odd):
                                      // softmax column reads 2-way = free

  const int lane = threadIdx.x;       // one wave per block
  const int m0   = blockIdx.x * 64;   // 66048/64 = 1032 blocks exact;
                                      // 8256 % 64 == 0 -> no batch straddle

  // A: 4 phases of 16 rows; lane covers row ph*16+(lane>>2), 32B chunk lane&3
  const float* pA[MF];
  #pragma unroll
  for (int ph = 0; ph < MF; ++ph)
    pA[ph] = hs + (size_t)(m0 + ph * 16 + (lane >> 2)) * HD + (lane & 3) * 8;
  // bpermute byte addr: target lane t pulls src lane 4*(t&15) + (t>>4)
  const int bp = ((lane & 15) * 4 + (lane >> 4)) * 4;

  f32x4  acc[MF][NT] = {};            // 80 VGPR
  float4 abuf[3][MF][2];              // A depth-2 (96 VGPR)
  i32x4  bbuf[2][NT];                 // B depth-1 (40 VGPR)

  ALOAD4(0); ALOAD4(1);
  BLOAD4(0);

  #pragma unroll
  for (int ks = 0; ks < KSTEPS; ++ks) {
    ALOAD4(ks + 2);
    BLOAD4(ks + 1);

    s16x8 af[MF];
    #pragma unroll
    for (int mt = 0; mt < MF; ++mt) {
      float4 a0 = abuf[ks % 3][mt][0], a1 = abuf[ks % 3][mt][1];
      i32x4 av;
      av[0] = __builtin_amdgcn_ds_bpermute(bp, pack2(a0.x, a0.y));
      av[1] = __builtin_amdgcn_ds_bpermute(bp, pack2(a0.z, a0.w));
      av[2] = __builtin_amdgcn_ds_bpermute(bp, pack2(a1.x, a1.y));
      av[3] = __builtin_amdgcn_ds_bpermute(bp, pack2(a1.z, a1.w));
      af[mt] = __builtin_bit_cast(s16x8, av);
    }

    #pragma unroll
    for (int nt = 0; nt < NT; ++nt) {
      s16x8 bf = __builtin_bit_cast(s16x8, bbuf[ks & 1][nt]);
      #pragma unroll
      for (int mt = 0; mt < MF; ++mt)
        acc[mt][nt] = __builtin_amdgcn_mfma_f32_16x16x32_bf16(af[mt], bf, acc[mt][nt], 0, 0, 0);
    }
  }

  // ---- epilogue: wave-private LDS transpose + 3-wide softmax ----
  #pragma unroll
  for (int mt = 0; mt < MF; ++mt)
    #pragma unroll
    for (int nt = 0; nt < NT; ++nt)
      #pragma unroll
      for (int j = 0; j < 4; ++j)     // C/D: col = lane&15, row = 4*(lane>>4)+j
        lg[mt * 16 + (lane >> 4) * 4 + j][nt * 16 + (lane & 15)] = acc[mt][nt][j];
  __syncthreads();                    // single wave: just the lgkmcnt drain

  const int bidx = m0 / LSEQ;         // block-uniform
  const int l0   = m0 - bidx * LSEQ;
  #pragma unroll
  for (int it = 0; it < 24; ++it) {   // 24 relations x 64 tokens, g = it
    const int g    = it;              // wave-uniform
    const int tokl = lane;
    float x0 = lg[tokl][3 * g + 0] + bias[3 * g + 0];
    float x1 = lg[tokl][3 * g + 1] + bias[3 * g + 1];
    float x2 = lg[tokl][3 * g + 2] + bias[3 * g + 2];
    float mx = fmaxf(x0, fmaxf(x1, x2));
    float e0 = __expf(x0 - mx), e1 = __expf(x1 - mx), e2 = __expf(x2 - mx);
    float inv = 1.0f / (e0 + e1 + e2);
    size_t o = ((size_t)(bidx * RREL + g) * LSEQ + l0 + tokl) * 3;
    out[o + 0] = e0 * inv;
    out[o + 1] = e1 * inv;
    out[o + 2] = e2 * inv;
  }
}

// ---- fallback (no ws): R5-style 1-wave kernel, direct frag-order W loads ----
__global__ __launch_bounds__(64, 2)
void tagging_fb(const float* __restrict__ hs, const float* __restrict__ W,
                const float* __restrict__ bias, float* __restrict__ out) {
  __shared__ float lg[32][85];
  const int lane = threadIdx.x;
  const int m0   = blockIdx.x * 32;

  const float* pA0 = hs + (size_t)(m0 + (lane >> 2)) * HD + (lane & 3) * 8;
  const float* pA1 = pA0 + 16 * HD;
  const int bp = ((lane & 15) * 4 + (lane >> 4)) * 4;

  const float* pB[NT];
  #pragma unroll
  for (int nt = 0; nt < NT; ++nt)
    pB[nt] = W + (size_t)(nt * 16 + (lane & 15)) * HD + (lane >> 4) * 8;
  const bool b4ok = (lane & 15) < 8;

  f32x4  acc[2][NT] = {};
  float4 abuf[3][2][2];
  float4 fbf[2][NT][2];

#define FB_ALOAD(ks) do { if ((ks) < KSTEPS) {                     \
    const int s_ = (ks) % 3, o_ = (ks) * 32;                       \
    abuf[s_][0][0] = *(const float4*)(pA0 + o_);                   \
    abuf[s_][0][1] = *(const float4*)(pA0 + o_ + 4);               \
    abuf[s_][1][0] = *(const float4*)(pA1 + o_);                   \
    abuf[s_][1][1] = *(const float4*)(pA1 + o_ + 4);               \
  } } while (0)

#define FB_BLOAD(ks) do { if ((ks) < KSTEPS) {                     \
    _Pragma("unroll")                                              \
    for (int nt_ = 0; nt_ < 4; ++nt_) {                            \
      fbf[(ks) & 1][nt_][0] = *(const float4*)(pB[nt_] + (ks)*32); \
      fbf[(ks) & 1][nt_][1] = *(const float4*)(pB[nt_] + (ks)*32 + 4); \
    }                                                              \
    if (b4ok) {                                                    \
      fbf[(ks) & 1][4][0] = *(const float4*)(pB[4] + (ks)*32);     \
      fbf[(ks) & 1][4][1] = *(const float4*)(pB[4] + (ks)*32 + 4); \
    } else {                                                       \
      fbf[(ks) & 1][4][0] = make_float4(0.f,0.f,0.f,0.f);          \
      fbf[(ks) & 1][4][1] = make_float4(0.f,0.f,0.f,0.f);          \
    }                                                              \
  } } while (0)

  FB_ALOAD(0); FB_ALOAD(1);
  FB_BLOAD(0);

  #pragma unroll
  for (int ks = 0; ks < KSTEPS; ++ks) {
    FB_ALOAD(ks + 2);
    FB_BLOAD(ks + 1);
    s16x8 af[2];
    #pragma unroll
    for (int mt = 0; mt < 2; ++mt) {
      float4 a0 = abuf[ks % 3][mt][0], a1 = abuf[ks % 3][mt][1];
      i32x4 av;
      av[0] = __builtin_amdgcn_ds_bpermute(bp, pack2(a0.x, a0.y));
      av[1] = __builtin_amdgcn_ds_bpermute(bp, pack2(a0.z, a0.w));
      av[2] = __builtin_amdgcn_ds_bpermute(bp, pack2(a1.x, a1.y));
      av[3] = __builtin_amdgcn_ds_bpermute(bp, pack2(a1.z, a1.w));
      af[mt] = __builtin_bit_cast(s16x8, av);
    }
    #pragma unroll
    for (int nt = 0; nt < NT; ++nt) {
      float4 b0 = fbf[ks & 1][nt][0], b1 = fbf[ks & 1][nt][1];
      i32x4 bv;
      bv[0] = pack2(b0.x, b0.y); bv[1] = pack2(b0.z, b0.w);
      bv[2] = pack2(b1.x, b1.y); bv[3] = pack2(b1.z, b1.w);
      s16x8 bf = __builtin_bit_cast(s16x8, bv);
      acc[0][nt] = __builtin_amdgcn_mfma_f32_16x16x32_bf16(af[0], bf, acc[0][nt], 0, 0, 0);
      acc[1][nt] = __builtin_amdgcn_mfma_f32_16x16x32_bf16(af[1], bf, acc[1][nt], 0, 0, 0);
    }
  }

  #pragma unroll
  for (int mt = 0; mt < 2; ++mt)
    #pragma unroll
    for (int nt = 0; nt < NT; ++nt)
      #pragma unroll
      for (int j = 0; j < 4; ++j)
        lg[mt * 16 + (lane >> 4) * 4 + j][nt * 16 + (lane & 15)] = acc[mt][nt][j];
  __syncthreads();

  const int bidx = m0 / LSEQ;
  const int l0   = m0 - bidx * LSEQ;
  #pragma unroll
  for (int it = 0; it < 12; ++it) {
    int flat = it * 64 + lane;
    int g    = flat >> 5;
    int tokl = flat & 31;
    float x0 = lg[tokl][3 * g + 0] + bias[3 * g + 0];
    float x1 = lg[tokl][3 * g + 1] + bias[3 * g + 1];
    float x2 = lg[tokl][3 * g + 2] + bias[3 * g + 2];
    float mx = fmaxf(x0, fmaxf(x1, x2));
    float e0 = __expf(x0 - mx), e1 = __expf(x1 - mx), e2 = __expf(x2 - mx);
    float inv = 1.0f / (e0 + e1 + e2);
    size_t o = ((size_t)(bidx * RREL + g) * LSEQ + l0 + tokl) * 3;
    out[o + 0] = e0 * inv;
    out[o + 1] = e1 * inv;
    out[o + 2] = e2 * inv;
  }
}

extern "C" void kernel_launch(void* const* d_in, const int* in_sizes, int n_in,
                              void* d_out, int out_size, void* d_ws, size_t ws_size,
                              hipStream_t stream) {
  (void)in_sizes; (void)n_in; (void)out_size;
  const float* hs   = (const float*)d_in[0];  // (8, 8256, 768) fp32
  const float* W    = (const float*)d_in[1];  // (24, 3, 768)   fp32
  const float* bias = (const float*)d_in[2];  // (24, 3)        fp32
  float* out = (float*)d_out;                 // (8, 24, 8256, 3) fp32

  const size_t needB = (size_t)KSTEPS * NT * 64 * 8 * 2;   // 122880 B
  if (d_ws && ws_size >= needB) {
    hipLaunchKernelGGL(conv_w_kernel, dim3(30), dim3(256), 0, stream,
                       W, (unsigned short*)d_ws);
    hipLaunchKernelGGL(tagging_m64, dim3(1032), dim3(64), 0, stream,
                       hs, bias, (const i32x4*)d_ws, out);
  } else {
    hipLaunchKernelGGL(tagging_fb, dim3(2064), dim3(64), 0, stream,
                       hs, W, bias, out);
  }
}